// Round 1
// baseline (21.198 us; speedup 1.0000x reference)
//
#include <hip/hip_runtime.h>

// x: (8,512,1024) f32 -> 4096 rows of dim 1024.
// out: (8,512,16) f32.
// Ops: 10x Z_j (j=0..9, bit 9-j), 3x X (masks 512,256,128), 3x Y (=0 for real states).
__global__ __launch_bounds__(256) void pauli_exp_kernel(const float* __restrict__ x,
                                                        float* __restrict__ out) {
    const int n = blockIdx.x;        // row 0..4095
    const int t = threadIdx.x;       // 0..255

    __shared__ float row[1024];
    __shared__ float red[4][13];

    const float4 v = reinterpret_cast<const float4*>(x + (size_t)n * 1024)[t];
    reinterpret_cast<float4*>(row)[t] = v;

    float acc[13];
#pragma unroll
    for (int i = 0; i < 13; ++i) acc[i] = 0.f;

    const int base = t * 4;
    float xs[4] = {v.x, v.y, v.z, v.w};

    // Z expectations: signed sums of squares (register-only)
#pragma unroll
    for (int e = 0; e < 4; ++e) {
        const int d = base + e;
        const float sq = xs[e] * xs[e];
#pragma unroll
        for (int j = 0; j < 10; ++j) {
            acc[j] += ((d >> (9 - j)) & 1) ? -sq : sq;
        }
    }

    __syncthreads();

    // X expectations: correlation with bit-flipped partner (masks >= 128, so
    // (base+e)^m == (base^m)+e -> 16B-contiguous LDS reads per thread)
#pragma unroll
    for (int e = 0; e < 4; ++e) {
        const int d = base + e;
        const float xv = xs[e];
        acc[10] += xv * row[d ^ 512];
        acc[11] += xv * row[d ^ 256];
        acc[12] += xv * row[d ^ 128];
    }

    // Wave (64-lane) butterfly reduce for each accumulator
#pragma unroll
    for (int i = 0; i < 13; ++i) {
        float a = acc[i];
#pragma unroll
        for (int off = 32; off > 0; off >>= 1)
            a += __shfl_down(a, off, 64);
        acc[i] = a;
    }

    const int wave = t >> 6;
    const int lane = t & 63;
    if (lane == 0) {
#pragma unroll
        for (int i = 0; i < 13; ++i) red[wave][i] = acc[i];
    }
    __syncthreads();

    if (t < 16) {
        float r = 0.f;
        if (t < 13) r = red[0][t] + red[1][t] + red[2][t] + red[3][t];
        out[(size_t)n * 16 + t] = r;  // ops 13..15 (single Y, real psi) are exactly 0
    }
}

extern "C" void kernel_launch(void* const* d_in, const int* in_sizes, int n_in,
                              void* d_out, int out_size, void* d_ws, size_t ws_size,
                              hipStream_t stream) {
    const float* x = (const float*)d_in[0];
    float* out = (float*)d_out;
    const int n_rows = in_sizes[0] / 1024;  // 4096
    pauli_exp_kernel<<<n_rows, 256, 0, stream>>>(x, out);
}

// Round 2
// 18.992 us; speedup vs baseline: 1.1161x; 1.1161x over previous
//
#include <hip/hip_runtime.h>

// x: (8,512,1024) f32 -> 4096 rows of dim 1024.  out: (8,512,16) f32.
// Op o semantics (derived from the Pauli strings; states are real):
//   o=0..9  : Z on bit (9-o)  -> signed sum of squares
//   o=10..12: X with flip mask 512,256,128 -> correlation sum
//   o=13..15: single Y, real psi -> exactly 0
//
// One wave per row. Lane layout: element d = k*256 + lane*4 + e,
// k = which float4 batch (d bits 9:8), lane = d bits 7:2, e = d bits 1:0.
__global__ __launch_bounds__(256) void pauli_exp_wave(const float* __restrict__ x,
                                                      float* __restrict__ out) {
    const int wave = threadIdx.x >> 6;
    const int lane = threadIdx.x & 63;
    const int row  = blockIdx.x * 4 + wave;   // 0..4095

    const float4* rp = reinterpret_cast<const float4*>(x) + (size_t)row * 256;
    const float4 v0 = rp[lane];
    const float4 v1 = rp[lane + 64];
    const float4 v2 = rp[lane + 128];
    const float4 v3 = rp[lane + 192];

    // --- per-k square combos ---
    // t_k = |v_k|^2 ; A_k = x^2+y^2-z^2-w^2 (sign by e bit1) ; B_k = x^2-y^2+z^2-w^2 (e bit0)
    float t[4], A = 0.f, B = 0.f;
    {
        const float4 vv[4] = {v0, v1, v2, v3};
#pragma unroll
        for (int k = 0; k < 4; ++k) {
            const float sx = vv[k].x * vv[k].x;
            const float sy = vv[k].y * vv[k].y;
            const float sz = vv[k].z * vv[k].z;
            const float sw = vv[k].w * vv[k].w;
            const float sxy = sx + sy, szw = sz + sw;
            t[k] = sxy + szw;
            A += sxy - szw;
            B += (sx - sy) + (sz - sw);
        }
    }
    const float p = t[0] + t[1], q = t[2] + t[3];
    const float S   = p + q;
    const float z9  = p - q;                        // Z bit9 (k bit1)
    const float z8  = (t[0] + t[2]) - (t[1] + t[3]); // Z bit8 (k bit0)

    // Z bits 7..2: sign = (-1)^(lane bit (b-2)) applied to S per lane
    const float z7 = (lane & 32) ? -S : S;
    const float z6 = (lane & 16) ? -S : S;
    const float z5 = (lane & 8)  ? -S : S;
    const float z4 = (lane & 4)  ? -S : S;
    const float z3 = (lane & 2)  ? -S : S;
    const float z2 = (lane & 1)  ? -S : S;

    // X mask 512 (k bit1 flip): 2*(v0.v2 + v1.v3); X mask 256 (k bit0): 2*(v0.v1 + v2.v3)
    const float d02 = v0.x*v2.x + v0.y*v2.y + v0.z*v2.z + v0.w*v2.w;
    const float d13 = v1.x*v3.x + v1.y*v3.y + v1.z*v3.z + v1.w*v3.w;
    const float d01 = v0.x*v1.x + v0.y*v1.y + v0.z*v1.z + v0.w*v1.w;
    const float d23 = v2.x*v3.x + v2.y*v3.y + v2.z*v3.z + v2.w*v3.w;
    const float x512 = 2.f * (d02 + d13);
    const float x256 = 2.f * (d01 + d23);

    // X mask 128 (lane bit5 flip): sum_k dot(v_k, shfl_xor(v_k, 32))
    float x128 = 0.f;
    {
#pragma unroll
        for (int k = 0; k < 4; ++k) {
            const float4 vv = (k == 0) ? v0 : (k == 1) ? v1 : (k == 2) ? v2 : v3;
            x128 += vv.x * __shfl_xor(vv.x, 32, 64);
            x128 += vv.y * __shfl_xor(vv.y, 32, 64);
            x128 += vv.z * __shfl_xor(vv.z, 32, 64);
            x128 += vv.w * __shfl_xor(vv.w, 32, 64);
        }
    }

    // --- 13-value butterfly reduce across the wave (static indexing only) ---
    float r[13] = {z9, z8, z7, z6, z5, z4, z3, z2, A, B, x512, x256, x128};
#pragma unroll
    for (int i = 0; i < 13; ++i) {
        float a = r[i];
#pragma unroll
        for (int off = 32; off > 0; off >>= 1)
            a += __shfl_xor(a, off, 64);
        r[i] = a;
    }

    if (lane == 0) {
        float4* op = reinterpret_cast<float4*>(out) + (size_t)row * 4;
        op[0] = make_float4(r[0], r[1], r[2],  r[3]);
        op[1] = make_float4(r[4], r[5], r[6],  r[7]);
        op[2] = make_float4(r[8], r[9], r[10], r[11]);
        op[3] = make_float4(r[12], 0.f, 0.f, 0.f);   // ops 13..15 (Y, real psi) = 0
    }
}

extern "C" void kernel_launch(void* const* d_in, const int* in_sizes, int n_in,
                              void* d_out, int out_size, void* d_ws, size_t ws_size,
                              hipStream_t stream) {
    const float* x = (const float*)d_in[0];
    float* out = (float*)d_out;
    const int n_rows = in_sizes[0] / 1024;      // 4096
    pauli_exp_wave<<<n_rows / 4, 256, 0, stream>>>(x, out);
}

// Round 3
// 10.662 us; speedup vs baseline: 1.9882x; 1.7813x over previous
//
#include <hip/hip_runtime.h>

// x: (8,512,1024) f32 -> 4096 rows of dim 1024.  out: (8,512,16) f32.
// Op o semantics (states real):
//   o=0..9  : Z on bit (9-o) -> signed sum of squares
//   o=10..12: X with flip mask 512,256,128 -> 2*correlation sum
//   o=13..15: single Y on real psi -> exactly 0
//
// One wave per row. Lane layout (float2 loads): element d decomposes as
//   d = k*256 + e*128 + lane*2 + c   (k=d[9:8], e=d[7], lane=d[6:1], c=d[0])
// => masks 512 (k bit1), 256 (k bit0), 128 (e) are ALL in-register.
__global__ __launch_bounds__(256) void pauli_exp_wave2(const float* __restrict__ x,
                                                       float* __restrict__ out) {
    const int wave = threadIdx.x >> 6;
    const int lane = threadIdx.x & 63;
    const int row  = blockIdx.x * 4 + wave;          // 0..4095

    const float2* rp = reinterpret_cast<const float2*>(x) + (size_t)row * 512;
    float2 v[4][2];
#pragma unroll
    for (int k = 0; k < 4; ++k)
#pragma unroll
        for (int e = 0; e < 2; ++e)
            v[k][e] = rp[k * 128 + e * 64 + lane];

    // squares
    float t[4][2], zc = 0.f;
#pragma unroll
    for (int k = 0; k < 4; ++k)
#pragma unroll
        for (int e = 0; e < 2; ++e) {
            const float sx = v[k][e].x * v[k][e].x;
            const float sy = v[k][e].y * v[k][e].y;
            t[k][e] = sx + sy;
            zc += sx - sy;                            // op9: Z on bit0 (= c)
        }
    const float tk0 = t[0][0] + t[0][1];
    const float tk1 = t[1][0] + t[1][1];
    const float tk2 = t[2][0] + t[2][1];
    const float tk3 = t[3][0] + t[3][1];
    const float S  = (tk0 + tk1) + (tk2 + tk3);
    const float z9 = (tk0 + tk1) - (tk2 + tk3);       // op0: bit9 (k bit1)
    const float z8 = (tk0 + tk2) - (tk1 + tk3);       // op1: bit8 (k bit0)
    const float z7 = (t[0][0] + t[1][0] + t[2][0] + t[3][0])
                   - (t[0][1] + t[1][1] + t[2][1] + t[3][1]);  // op2: bit7 (e)

    // ops 3..8: Z on bits 6..1 = lane bits 5..0 -> per-lane sign on S
    const float z6 = (lane & 32) ? -S : S;
    const float z5 = (lane & 16) ? -S : S;
    const float z4 = (lane & 8)  ? -S : S;
    const float z3 = (lane & 4)  ? -S : S;
    const float z2 = (lane & 2)  ? -S : S;
    const float z1 = (lane & 1)  ? -S : S;

    // X correlations -- all in-register with this layout
    auto dot2 = [](float2 a, float2 b) { return a.x * b.x + a.y * b.y; };
    float x512 = 0.f, x256 = 0.f, x128 = 0.f;
#pragma unroll
    for (int e = 0; e < 2; ++e) {
        x512 += dot2(v[0][e], v[2][e]) + dot2(v[1][e], v[3][e]);  // k bit1 flip
        x256 += dot2(v[0][e], v[1][e]) + dot2(v[2][e], v[3][e]);  // k bit0 flip
    }
#pragma unroll
    for (int k = 0; k < 4; ++k)
        x128 += dot2(v[k][0], v[k][1]);                           // e flip
    x512 *= 2.f; x256 *= 2.f; x128 *= 2.f;

    // 16-value reduce-scatter: after 4 halving stages lane l holds w[l&15]
    // summed over its 16-lane group; 2 more stages finish the 64-lane sum.
    float w[16] = {z9, z8, z7, z6, z5, z4, z3, z2, z1, zc,
                   x512, x256, x128, 0.f, 0.f, 0.f};
    float w8[8];
    {
        const bool hi = lane & 1;
#pragma unroll
        for (int i = 0; i < 8; ++i) {
            const float keep = hi ? w[2 * i + 1] : w[2 * i];
            const float send = hi ? w[2 * i]     : w[2 * i + 1];
            w8[i] = keep + __shfl_xor(send, 1, 64);
        }
    }
    float w4[4];
    {
        const bool hi = lane & 2;
#pragma unroll
        for (int i = 0; i < 4; ++i) {
            const float keep = hi ? w8[2 * i + 1] : w8[2 * i];
            const float send = hi ? w8[2 * i]     : w8[2 * i + 1];
            w4[i] = keep + __shfl_xor(send, 2, 64);
        }
    }
    float w2[2];
    {
        const bool hi = lane & 4;
#pragma unroll
        for (int i = 0; i < 2; ++i) {
            const float keep = hi ? w4[2 * i + 1] : w4[2 * i];
            const float send = hi ? w4[2 * i]     : w4[2 * i + 1];
            w2[i] = keep + __shfl_xor(send, 4, 64);
        }
    }
    float a;
    {
        const bool hi = lane & 8;
        const float keep = hi ? w2[1] : w2[0];
        const float send = hi ? w2[0] : w2[1];
        a = keep + __shfl_xor(send, 8, 64);
    }
    a += __shfl_xor(a, 16, 64);
    a += __shfl_xor(a, 32, 64);

    // lane l (<16) holds op l exactly (13..15 are the padded zeros)
    if (lane < 16) out[(size_t)row * 16 + lane] = a;
}

extern "C" void kernel_launch(void* const* d_in, const int* in_sizes, int n_in,
                              void* d_out, int out_size, void* d_ws, size_t ws_size,
                              hipStream_t stream) {
    const float* x = (const float*)d_in[0];
    float* out = (float*)d_out;
    const int n_rows = in_sizes[0] / 1024;           // 4096
    pauli_exp_wave2<<<n_rows / 4, 256, 0, stream>>>(x, out);
}

// Round 4
// 9.591 us; speedup vs baseline: 2.2102x; 1.1117x over previous
//
#include <hip/hip_runtime.h>

// x: (8,512,1024) f32 -> 4096 rows of 1024.  out: (8,512,16) f32.
// Ops: o=0..9 Z on qubit-bit (9-o) -> signed sum of squares;
//      o=10..12 X with flip mask 512/256/128 -> 2*correlation;
//      o=13..15 single Y on real state -> exactly 0.
//
// HALF-WAVE per row: lanes [0,32) -> row base, lanes [32,64) -> base+1.
// Element d = r*128 + l5*4 + c  (r = d[9:7] register index, l5 = d[6:2] = lane&31,
// c = d[1:0] within float4). All flip masks (512,256,128) are register-index bits
// -> zero cross-lane traffic for the X ops.
__global__ __launch_bounds__(256) void pauli_exp_half(const float* __restrict__ x,
                                                      float* __restrict__ out) {
    const int wave = threadIdx.x >> 6;
    const int lane = threadIdx.x & 63;
    const int l5   = lane & 31;
    const int row  = blockIdx.x * 8 + wave * 2 + (lane >> 5);   // 0..4095

    const float4* rp = reinterpret_cast<const float4*>(x) + (size_t)row * 256;
    float4 v[8];
#pragma unroll
    for (int r = 0; r < 8; ++r) v[r] = rp[r * 32 + l5];

    // per-register squares: t[r] = |v_r|^2, A/B = component-sign sums (bits 1,0)
    float t[8], A = 0.f, B = 0.f;
#pragma unroll
    for (int r = 0; r < 8; ++r) {
        const float sx = v[r].x * v[r].x;
        const float sy = v[r].y * v[r].y;
        const float sz = v[r].z * v[r].z;
        const float sw = v[r].w * v[r].w;
        t[r] = (sx + sy) + (sz + sw);
        A += (sx + sy) - (sz + sw);      // op8: Z bit1 (c bit1)
        B += (sx - sy) + (sz - sw);      // op9: Z bit0 (c bit0)
    }
    const float t03 = (t[0] + t[1]) + (t[2] + t[3]);
    const float t47 = (t[4] + t[5]) + (t[6] + t[7]);
    const float S   = t03 + t47;
    const float z9  = t03 - t47;                                          // op0 (r bit2)
    const float z8  = ((t[0] + t[1]) + (t[4] + t[5])) - ((t[2] + t[3]) + (t[6] + t[7])); // op1 (r bit1)
    const float z7  = ((t[0] + t[2]) + (t[4] + t[6])) - ((t[1] + t[3]) + (t[5] + t[7])); // op2 (r bit0)

    // ops 3..7: Z on d-bits 6..2 = l5 bits 4..0 -> per-lane sign on S
    const float z6 = (l5 & 16) ? -S : S;
    const float z5 = (l5 & 8)  ? -S : S;
    const float z4 = (l5 & 4)  ? -S : S;
    const float z3 = (l5 & 2)  ? -S : S;
    const float z2 = (l5 & 1)  ? -S : S;

    // X correlations: all register-pair dots (flip = register-index bit)
    auto dot4 = [](const float4& a, const float4& b) {
        return (a.x * b.x + a.y * b.y) + (a.z * b.z + a.w * b.w);
    };
    const float x512 = 2.f * ((dot4(v[0], v[4]) + dot4(v[1], v[5])) +
                              (dot4(v[2], v[6]) + dot4(v[3], v[7])));   // op10 (bit9)
    const float x256 = 2.f * ((dot4(v[0], v[2]) + dot4(v[1], v[3])) +
                              (dot4(v[4], v[6]) + dot4(v[5], v[7])));   // op11 (bit8)
    const float x128 = 2.f * ((dot4(v[0], v[1]) + dot4(v[2], v[3])) +
                              (dot4(v[4], v[5]) + dot4(v[6], v[7])));   // op12 (bit7)

    // 16-value reduce-scatter within each 32-lane half (xor 1,2,4,8 then 16):
    // after the 4 halving stages lane l holds w[l&15] summed over its 16-group;
    // the xor-16 add completes the 32-lane (one-row) sum. No xor-32 (two rows!).
    float w[16] = {z9, z8, z7, z6, z5, z4, z3, z2, A, B,
                   x512, x256, x128, 0.f, 0.f, 0.f};
    float w8[8];
    {
        const bool hi = lane & 1;
#pragma unroll
        for (int i = 0; i < 8; ++i) {
            const float keep = hi ? w[2 * i + 1] : w[2 * i];
            const float send = hi ? w[2 * i]     : w[2 * i + 1];
            w8[i] = keep + __shfl_xor(send, 1, 64);
        }
    }
    float w4[4];
    {
        const bool hi = lane & 2;
#pragma unroll
        for (int i = 0; i < 4; ++i) {
            const float keep = hi ? w8[2 * i + 1] : w8[2 * i];
            const float send = hi ? w8[2 * i]     : w8[2 * i + 1];
            w4[i] = keep + __shfl_xor(send, 2, 64);
        }
    }
    float w2[2];
    {
        const bool hi = lane & 4;
#pragma unroll
        for (int i = 0; i < 2; ++i) {
            const float keep = hi ? w2[0] * 0.f + (hi ? w4[2 * i + 1] : w4[2 * i]) : w4[2 * i];
            // (simple form below)
            const float k2 = hi ? w4[2 * i + 1] : w4[2 * i];
            const float s2 = hi ? w4[2 * i]     : w4[2 * i + 1];
            w2[i] = k2 + __shfl_xor(s2, 4, 64);
            (void)keep;
        }
    }
    float a;
    {
        const bool hi = lane & 8;
        const float keep = hi ? w2[1] : w2[0];
        const float send = hi ? w2[0] : w2[1];
        a = keep + __shfl_xor(send, 8, 64);
    }
    a += __shfl_xor(a, 16, 64);   // completes the 32-lane (per-row) sum

    if (l5 < 16) out[(size_t)row * 16 + l5] = a;   // lane l5 holds op l5; 13..15 = 0
}

extern "C" void kernel_launch(void* const* d_in, const int* in_sizes, int n_in,
                              void* d_out, int out_size, void* d_ws, size_t ws_size,
                              hipStream_t stream) {
    const float* x = (const float*)d_in[0];
    float* out = (float*)d_out;
    const int n_rows = in_sizes[0] / 1024;        // 4096
    pauli_exp_half<<<n_rows / 8, 256, 0, stream>>>(x, out);
}